// Round 7
// baseline (634.407 us; speedup 1.0000x reference)
//
#include <hip/hip_runtime.h>
#include <cstdint>

typedef unsigned int uint;
typedef unsigned short ushort_t;
typedef unsigned long long ull;
typedef __attribute__((ext_vector_type(8))) short bf16x8;
typedef __attribute__((ext_vector_type(4))) float f32x4;
typedef __attribute__((ext_vector_type(2))) float f32x2;

#define B_   16
#define N_   2048
#define S_   512
#define G_   8192       // B_*S_
#define DIN  64
#define DOUT 128
#define K_   32
#define ATS  136        // gemm2 actT row stride (bf16)
#define ATS1 72         // gemm1 xgT row stride (bf16)

__device__ __forceinline__ uint bf16b(float f) {
  uint u = __float_as_uint(f);
  return (u + 0x7fffu + ((u >> 16) & 1u)) >> 16;
}
__device__ __forceinline__ float bf2f(uint b) { return __uint_as_float(b << 16); }

// u64 max with one DPP step applied to both halves (bc=1 zero-fill = identity for max)
template<int CTRL, int RM>
__device__ __forceinline__ ull dpp_max_step(ull x) {
  uint lo = (uint)x, hi = (uint)(x >> 32);
  uint nlo = (uint)__builtin_amdgcn_update_dpp((int)lo, (int)lo, CTRL, RM, 0xf, true);
  uint nhi = (uint)__builtin_amdgcn_update_dpp((int)hi, (int)hi, CTRL, RM, 0xf, true);
  ull y = ((ull)nhi << 32) | (ull)nlo;
  return x > y ? x : y;
}

// ---------------- FPS: ONE WAVE per batch — zero barriers, exact fp32 -------------
// 32 pts/lane in float2 reg pairs; packed-f32 (v_pk) distance update (each half is
// an IEEE-rounded scalar op == __fadd_rn/__fmul_rn, same rounding order as numpy).
// Per-lane argmax: strict-> cmp keeps first index; cross-lane: u64 (dist|~j) DPP max
// -> readlane(63) -> uniform far -> 3 offset-imm ds_reads for winner coords.
// Reference scan emits PRE-update far (idx[0]==0) -> emit at loop top.
__global__ __launch_bounds__(64) void fps_kernel(const float* __restrict__ coords,
                                                 int* __restrict__ fidx,
                                                 float* __restrict__ out_xyz) {
  int b = blockIdx.x;
  const float* cb = coords + (size_t)b * (N_ * 3);
  __shared__ float spt[3][N_];      // SoA coords for winner lookup
  int lane = threadIdx.x;
  f32x2 px[16], py[16], pz[16], dist[16];
  // load this lane's 32 contiguous points (96 floats) via 24 float4s
  {
    const float4* src4 = (const float4*)cb + lane * 24;
    float tmp[96];
#pragma unroll
    for (int t = 0; t < 24; ++t) {
      float4 v = src4[t];
      tmp[4 * t] = v.x; tmp[4 * t + 1] = v.y; tmp[4 * t + 2] = v.z; tmp[4 * t + 3] = v.w;
    }
#pragma unroll
    for (int i = 0; i < 16; ++i) {
      px[i].x = tmp[6 * i];     py[i].x = tmp[6 * i + 1]; pz[i].x = tmp[6 * i + 2];
      px[i].y = tmp[6 * i + 3]; py[i].y = tmp[6 * i + 4]; pz[i].y = tmp[6 * i + 5];
      dist[i].x = 1e10f; dist[i].y = 1e10f;
    }
#pragma unroll
    for (int i = 0; i < 16; ++i) {
      *(f32x2*)&spt[0][lane * 32 + 2 * i] = px[i];
      *(f32x2*)&spt[1][lane * 32 + 2 * i] = py[i];
      *(f32x2*)&spt[2][lane * 32 + 2 * i] = pz[i];
    }
  }
  float cx = cb[0], cy = cb[1], cz = cb[2];
  uint far = 0;
  uint jbase = (uint)lane * 32;
  for (int s = 0; s < S_; ++s) {
    // emit pre-update winner (lane0: index+x, lane1: y, lane2: z)
    if (lane < 3) {
      float v = lane == 0 ? cx : (lane == 1 ? cy : cz);
      out_xyz[(b * S_ + s) * 3 + lane] = v;
      if (lane == 0) fidx[b * S_ + s] = (int)far;
    }
    f32x2 c2x = {cx, cx}, c2y = {cy, cy}, c2z = {cz, cz};
    float bestv = -1.f; uint bestloc = 0;
#pragma unroll
    for (int i = 0; i < 16; ++i) {
      f32x2 dx, dy, dz, qx, qy, qz, s1, s2;
      asm("v_pk_add_f32 %0, %1, %2 neg_lo:[0,1] neg_hi:[0,1]" : "=v"(dx) : "v"(px[i]), "v"(c2x));
      asm("v_pk_add_f32 %0, %1, %2 neg_lo:[0,1] neg_hi:[0,1]" : "=v"(dy) : "v"(py[i]), "v"(c2y));
      asm("v_pk_add_f32 %0, %1, %2 neg_lo:[0,1] neg_hi:[0,1]" : "=v"(dz) : "v"(pz[i]), "v"(c2z));
      asm("v_pk_mul_f32 %0, %1, %1" : "=v"(qx) : "v"(dx));
      asm("v_pk_mul_f32 %0, %1, %1" : "=v"(qy) : "v"(dy));
      asm("v_pk_mul_f32 %0, %1, %1" : "=v"(qz) : "v"(dz));
      asm("v_pk_add_f32 %0, %1, %2" : "=v"(s1) : "v"(qx), "v"(qy));
      asm("v_pk_add_f32 %0, %1, %2" : "=v"(s2) : "v"(s1), "v"(qz));
      float n0 = fminf(dist[i].x, s2.x);
      float n1 = fminf(dist[i].y, s2.y);
      dist[i].x = n0; dist[i].y = n1;
      bool g0 = n0 > bestv; bestv = g0 ? n0 : bestv; bestloc = g0 ? (uint)(2 * i) : bestloc;
      bool g1 = n1 > bestv; bestv = g1 ? n1 : bestv; bestloc = g1 ? (uint)(2 * i + 1) : bestloc;
    }
    ull best = ((ull)__float_as_uint(bestv) << 32) | (ull)(~(jbase + bestloc));
    best = dpp_max_step<0x111, 0xf>(best);   // row_shr:1
    best = dpp_max_step<0x112, 0xf>(best);   // row_shr:2
    best = dpp_max_step<0x114, 0xf>(best);   // row_shr:4
    best = dpp_max_step<0x118, 0xf>(best);   // row_shr:8
    best = dpp_max_step<0x142, 0xa>(best);   // row_bcast:15 -> rows 1,3
    best = dpp_max_step<0x143, 0xc>(best);   // row_bcast:31 -> rows 2,3
    uint klo = (uint)__builtin_amdgcn_readlane((int)(uint)best, 63);
    far = ~klo;                               // uniform winner index
    cx = spt[0][far]; cy = spt[1][far]; cz = spt[2][far];  // 3 parallel ds_reads
  }
}

// ---------------- Ball query: one wave per centroid ----------------
__global__ __launch_bounds__(256) void ball_kernel(const float* __restrict__ coords,
                                                   const int* __restrict__ fidx,
                                                   int* __restrict__ gidx) {
  int lane = threadIdx.x & 63;
  int g = __builtin_amdgcn_readfirstlane(blockIdx.x * 4 + (threadIdx.x >> 6));
  int b = g >> 9;
  const float* cb = coords + (size_t)b * (N_ * 3);
  int nf = fidx[g];
  float cx = cb[3 * nf], cy = cb[3 * nf + 1], cz = cb[3 * nf + 2];
  int* out = gidx + g * K_;
  int cnt = 0, first = 0;
  bool hasfirst = false;
  for (int base = 0; base < N_; base += 64) {
    int j = base + lane;
    float dx = __fsub_rn(cb[3 * j], cx);
    float dy = __fsub_rn(cb[3 * j + 1], cy);
    float dz = __fsub_rn(cb[3 * j + 2], cz);
    float d = __fadd_rn(__fadd_rn(__fmul_rn(dx, dx), __fmul_rn(dy, dy)), __fmul_rn(dz, dz));
    bool in = (d <= 0.25f);     // kept iff sqr <= r^2 (ref excludes sqr > r^2)
    ull m = __ballot(in);
    if (in) {
      int pos = cnt + __popcll(m & ((1ull << lane) - 1ull));
      if (pos < K_) out[pos] = j;
    }
    if (!hasfirst && m) { first = base + (__ffsll((long long)m) - 1); hasfirst = true; }
    cnt += __popcll(m);
    if (cnt >= K_) break;
  }
  if (cnt < K_) {
    for (int p = cnt + lane; p < K_; p += 64) out[p] = first;
  }
}

// ---------------- prep: B-fragment packs for both GEMMs ----------------
__global__ __launch_bounds__(256) void prep_kernel(const float* __restrict__ W1,
                                                   const float* __restrict__ W2,
                                                   ushort_t* __restrict__ Bp1,
                                                   ushort_t* __restrict__ Bpd,
                                                   ushort_t* __restrict__ Bp2) {
  int i = blockIdx.x * 256 + threadIdx.x;   // 16384
  int j2 = i & 7, l = (i >> 3) & 63;
  {
    int kc = (i >> 9) & 3, nt = i >> 11;
    int o2 = nt * 16 + (l & 15);
    int c2 = kc * 32 + ((l >> 4) * 8) + j2;
    Bp2[i] = (ushort_t)bf16b(W2[o2 * 128 + c2]);
  }
  if (i < 8192) {
    int kc = (i >> 9) & 1, nt = (i >> 10) & 7;
    int o2 = nt * 16 + (l & 15);
    int c2 = kc * 32 + ((l >> 4) * 8) + j2;
    float wa = W1[o2 * 128 + c2];
    float wb = W1[o2 * 128 + 64 + c2];
    Bp1[i] = (ushort_t)bf16b(wa);
    Bpd[i] = (ushort_t)bf16b(wb - wa);
  }
}

// ---------------- GEMM1 (MFMA bf16): h1T[g][k][o] = W1a@xg + (W1b-W1a)@ctr ------
__global__ __launch_bounds__(256) void gemm1_kernel(const float* __restrict__ x,
    const int* __restrict__ fidx, const int* __restrict__ gidx,
    const ushort_t* __restrict__ Bp1, const ushort_t* __restrict__ Bpd,
    ushort_t* __restrict__ h1T, float* __restrict__ psum, float* __restrict__ psq) {
  __shared__ ushort_t xgT[4][32 * ATS1];
  __shared__ float sctr[4][DIN];
  int tid = threadIdx.x;
  int lane = tid & 63, wid = tid >> 6;
  int g = __builtin_amdgcn_readfirstlane(blockIdx.x * 4 + wid);
  int b = g >> 9;
  const float* xb = x + (size_t)b * (DIN * N_);
  int nf = fidx[g];
  sctr[wid][lane] = xb[(size_t)lane * N_ + nf];   // lane = c (0..63)
  int kk = lane & 31, ch = lane >> 5;
  int gik = gidx[g * K_ + kk];
  ushort_t* xw = xgT[wid];
#pragma unroll
  for (int cc = 0; cc < 32; ++cc) {
    int c = ch * 32 + cc;
    xw[kk * ATS1 + c] = (ushort_t)bf16b(xb[(size_t)c * N_ + gik]);
  }
  __syncthreads();
  int l15 = lane & 15, r8 = (lane >> 4) * 8;
  f32x4 acc[2][8];
#pragma unroll
  for (int nt = 0; nt < 8; ++nt) acc[0][nt] = (f32x4){0.f, 0.f, 0.f, 0.f};
#pragma unroll
  for (int kc = 0; kc < 2; ++kc) {
    union { bf16x8 v; ushort_t u[8]; } cu;
#pragma unroll
    for (int j = 0; j < 8; ++j) cu.u[j] = (ushort_t)bf16b(sctr[wid][kc * 32 + r8 + j]);
#pragma unroll
    for (int nt = 0; nt < 8; ++nt) {
      bf16x8 bf = *(const bf16x8*)(Bpd + ((nt * 2 + kc) * 64 + lane) * 8);
      acc[0][nt] = __builtin_amdgcn_mfma_f32_16x16x32_bf16(cu.v, bf, acc[0][nt], 0, 0, 0);
    }
  }
#pragma unroll
  for (int nt = 0; nt < 8; ++nt) acc[1][nt] = acc[0][nt];
#pragma unroll
  for (int kc = 0; kc < 2; ++kc) {
    bf16x8 afrag[2];
#pragma unroll
    for (int mt = 0; mt < 2; ++mt)
      afrag[mt] = *(const bf16x8*)(xw + (mt * 16 + l15) * ATS1 + kc * 32 + r8);
#pragma unroll
    for (int nt = 0; nt < 8; ++nt) {
      bf16x8 bf = *(const bf16x8*)(Bp1 + ((nt * 2 + kc) * 64 + lane) * 8);
      acc[0][nt] = __builtin_amdgcn_mfma_f32_16x16x32_bf16(afrag[0], bf, acc[0][nt], 0, 0, 0);
      acc[1][nt] = __builtin_amdgcn_mfma_f32_16x16x32_bf16(afrag[1], bf, acc[1][nt], 0, 0, 0);
    }
  }
#pragma unroll
  for (int nt = 0; nt < 8; ++nt) {
    float s = 0.f, q = 0.f;
#pragma unroll
    for (int mt = 0; mt < 2; ++mt)
#pragma unroll
      for (int r = 0; r < 4; ++r) { float a = acc[mt][nt][r]; s += a; q = fmaf(a, a, q); }
    s += __shfl_xor(s, 16, 64); s += __shfl_xor(s, 32, 64);
    q += __shfl_xor(q, 16, 64); q += __shfl_xor(q, 32, 64);
    if (lane < 16) {
      int o = nt * 16 + lane;
      psum[o * G_ + g] = s; psq[o * G_ + g] = q;
    }
  }
#pragma unroll
  for (int mt = 0; mt < 2; ++mt)
#pragma unroll
    for (int r = 0; r < 4; ++r) {
      int k = mt * 16 + (lane >> 4) * 4 + r;
      ushort_t* dst = h1T + (size_t)g * 4096 + k * 128 + l15;
#pragma unroll
      for (int nt = 0; nt < 8; ++nt)
        dst[nt * 16] = (ushort_t)bf16b(acc[mt][nt][r]);
    }
}

// ---------------- BN finalize: per-channel mean/var -> scale/shift ----------------
__global__ __launch_bounds__(256) void bn_finalize(const float* __restrict__ psum,
    const float* __restrict__ psq, const float* __restrict__ gamma,
    const float* __restrict__ beta, float* __restrict__ bnp) {
  int o = blockIdx.x, tid = threadIdx.x;
  double s = 0.0, q = 0.0;
  for (int g = tid; g < G_; g += 256) { s += (double)psum[o * G_ + g]; q += (double)psq[o * G_ + g]; }
  __shared__ double ss[256], qq[256];
  ss[tid] = s; qq[tid] = q; __syncthreads();
  for (int off = 128; off > 0; off >>= 1) {
    if (tid < off) { ss[tid] += ss[tid + off]; qq[tid] += qq[tid + off]; }
    __syncthreads();
  }
  if (tid == 0) {
    double n = 262144.0;
    double mean = ss[0] / n, var = qq[0] / n - mean * mean;
    float scv = (float)((double)gamma[o] / sqrt(var + 1e-5));
    bnp[2 * o] = scv;
    bnp[2 * o + 1] = (float)((double)beta[o] - mean * (double)scv);
  }
}

// ---------------- GEMM2 (MFMA bf16): CT layout D[k][o], per-(g,o) stats ----------
__global__ __launch_bounds__(256) void gemm2_kernel(const ushort_t* __restrict__ h1T,
    const ushort_t* __restrict__ Bp2, const float* __restrict__ bnp1,
    float* __restrict__ psum, float* __restrict__ psq,
    float* __restrict__ hmax, float* __restrict__ hmin) {
  __shared__ ushort_t actT[4][32 * ATS];
  int tid = threadIdx.x;
  int lane = tid & 63, wid = tid >> 6;
  int g = __builtin_amdgcn_readfirstlane(blockIdx.x * 4 + wid);
  ushort_t* aw = actT[wid];
  int c0 = (lane & 15) * 8;
  float s1[8], t1[8];
#pragma unroll
  for (int jj = 0; jj < 8; ++jj) { s1[jj] = bnp1[2 * (c0 + jj)]; t1[jj] = bnp1[2 * (c0 + jj) + 1]; }
  const uint4* src = (const uint4*)(h1T + (size_t)g * 4096);
#pragma unroll
  for (int t = 0; t < 8; ++t) {
    int idx = t * 64 + lane;
    uint4 v = src[idx];
    int k = idx >> 4;
    uint w[4] = {v.x, v.y, v.z, v.w};
    uint o4[4];
#pragma unroll
    for (int p2 = 0; p2 < 4; ++p2) {
      float a0 = fmaxf(fmaf(bf2f(w[p2] & 0xffffu), s1[2 * p2], t1[2 * p2]), 0.f);
      float a1 = fmaxf(fmaf(bf2f(w[p2] >> 16), s1[2 * p2 + 1], t1[2 * p2 + 1]), 0.f);
      o4[p2] = (bf16b(a1) << 16) | bf16b(a0);
    }
    *(uint4*)(aw + k * ATS + c0) = make_uint4(o4[0], o4[1], o4[2], o4[3]);
  }
  __syncthreads();
  f32x4 acc[2][8];
#pragma unroll
  for (int mt = 0; mt < 2; ++mt)
#pragma unroll
    for (int nt = 0; nt < 8; ++nt) acc[mt][nt] = (f32x4){0.f, 0.f, 0.f, 0.f};
#pragma unroll
  for (int kc = 0; kc < 4; ++kc) {
    bf16x8 afrag[2];
#pragma unroll
    for (int mt = 0; mt < 2; ++mt)
      afrag[mt] = *(const bf16x8*)(aw + (mt * 16 + (lane & 15)) * ATS + kc * 32 + (lane >> 4) * 8);
#pragma unroll
    for (int nt = 0; nt < 8; ++nt) {
      bf16x8 bfrag = *(const bf16x8*)(Bp2 + ((nt * 4 + kc) * 64 + lane) * 8);
      acc[0][nt] = __builtin_amdgcn_mfma_f32_16x16x32_bf16(afrag[0], bfrag, acc[0][nt], 0, 0, 0);
      acc[1][nt] = __builtin_amdgcn_mfma_f32_16x16x32_bf16(afrag[1], bfrag, acc[1][nt], 0, 0, 0);
    }
  }
#pragma unroll
  for (int nt = 0; nt < 8; ++nt) {
    float s = 0.f, q = 0.f, mx = -1e30f, mn = 1e30f;
#pragma unroll
    for (int mt = 0; mt < 2; ++mt)
#pragma unroll
      for (int r = 0; r < 4; ++r) {
        float a = acc[mt][nt][r];
        s += a; q = fmaf(a, a, q); mx = fmaxf(mx, a); mn = fminf(mn, a);
      }
    s += __shfl_xor(s, 16, 64); s += __shfl_xor(s, 32, 64);
    q += __shfl_xor(q, 16, 64); q += __shfl_xor(q, 32, 64);
    mx = fmaxf(mx, __shfl_xor(mx, 16, 64)); mx = fmaxf(mx, __shfl_xor(mx, 32, 64));
    mn = fminf(mn, __shfl_xor(mn, 16, 64)); mn = fminf(mn, __shfl_xor(mn, 32, 64));
    if (lane < 16) {
      int o = nt * 16 + lane;
      psum[o * G_ + g] = s; psq[o * G_ + g] = q;
      hmax[o * G_ + g] = mx; hmin[o * G_ + g] = mn;
    }
  }
}

// ---------------- pool: out[b,o,s] = relu(s2 * (s2>=0 ? max : min) + t2) ----------------
__global__ __launch_bounds__(256) void pool_kernel(const float* __restrict__ hmax,
    const float* __restrict__ hmin, const float* __restrict__ bnp2,
    float* __restrict__ out) {
  int i = blockIdx.x * 256 + threadIdx.x;   // 1,048,576 = (b*128+o)*512+s
  int s = i & 511;
  int o = (i >> 9) & 127;
  int b = i >> 16;
  int g = b * 512 + s;
  float scv = bnp2[2 * o], tf = bnp2[2 * o + 1];
  float v = (scv >= 0.f) ? hmax[o * G_ + g] : hmin[o * G_ + g];
  out[i] = fmaxf(fmaf(scv, v, tf), 0.f);
}

extern "C" void kernel_launch(void* const* d_in, const int* in_sizes, int n_in,
                              void* d_out, int out_size, void* d_ws, size_t ws_size,
                              hipStream_t stream) {
  const float* x      = (const float*)d_in[0];
  const float* coords = (const float*)d_in[1];
  const float* W1     = (const float*)d_in[2];
  const float* W2     = (const float*)d_in[3];
  const float* gamma1 = (const float*)d_in[4];
  const float* beta1  = (const float*)d_in[5];
  const float* gamma2 = (const float*)d_in[6];
  const float* beta2  = (const float*)d_in[7];
  float* out = (float*)d_out;
  char* ws = (char*)d_ws;
  ushort_t* h1T  = (ushort_t*)(ws);               // 67,108,864 B  (h1T[g][k][o] bf16)
  float* psum1 = (float*)(ws + 67108864);         // 4 MB each below
  float* psq1  = (float*)(ws + 71303168);
  float* psum2 = (float*)(ws + 75497472);
  float* psq2  = (float*)(ws + 79691776);
  float* hmax  = (float*)(ws + 83886080);
  float* hmin  = (float*)(ws + 88080384);
  ushort_t* Bp1 = (ushort_t*)(ws + 92274688);     // 16 KB
  ushort_t* Bpd = (ushort_t*)(ws + 92291072);     // 16 KB
  ushort_t* Bp2 = (ushort_t*)(ws + 92307456);     // 32 KB
  float* bnp1  = (float*)(ws + 92340224);
  float* bnp2  = (float*)(ws + 92341248);
  int* fidx    = (int*)(ws + 92342272);           // 32 KB
  int* gidx    = (int*)(ws + 92375040);           // 1 MB, end 93,423,616 B

  prep_kernel<<<64, 256, 0, stream>>>(W1, W2, Bp1, Bpd, Bp2);
  fps_kernel<<<16, 64, 0, stream>>>(coords, fidx, out);
  ball_kernel<<<2048, 256, 0, stream>>>(coords, fidx, gidx);
  gemm1_kernel<<<2048, 256, 0, stream>>>(x, fidx, gidx, Bp1, Bpd, h1T, psum1, psq1);
  bn_finalize<<<128, 256, 0, stream>>>(psum1, psq1, gamma1, beta1, bnp1);
  gemm2_kernel<<<2048, 256, 0, stream>>>(h1T, Bp2, bnp1, psum2, psq2, hmax, hmin);
  bn_finalize<<<128, 256, 0, stream>>>(psum2, psq2, gamma2, beta2, bnp2);
  pool_kernel<<<4096, 256, 0, stream>>>(hmax, hmin, bnp2, out + 24576);
}

// Round 8
// 382.802 us; speedup vs baseline: 1.6573x; 1.6573x over previous
//
#include <hip/hip_runtime.h>
#include <cstdint>

typedef unsigned int uint;
typedef unsigned short ushort_t;
typedef unsigned long long ull;
typedef __attribute__((ext_vector_type(8))) short bf16x8;
typedef __attribute__((ext_vector_type(4))) float f32x4;
typedef __attribute__((ext_vector_type(2))) float f32x2;

#define B_   16
#define N_   2048
#define S_   512
#define G_   8192       // B_*S_
#define DIN  64
#define DOUT 128
#define K_   32
#define ATS  136        // gemm2 actT row stride (bf16)
#define ATS1 72         // gemm1 xgT row stride (bf16)

__device__ __forceinline__ uint bf16b(float f) {
  uint u = __float_as_uint(f);
  return (u + 0x7fffu + ((u >> 16) & 1u)) >> 16;
}
__device__ __forceinline__ float bf2f(uint b) { return __uint_as_float(b << 16); }

template<int CTRL, int RM>
__device__ __forceinline__ float dpp_fmax_step(float x) {
  float y = __uint_as_float((uint)__builtin_amdgcn_update_dpp(
      (int)__float_as_uint(x), (int)__float_as_uint(x), CTRL, RM, 0xf, true));
  return fmaxf(x, y);   // bound_ctrl zero-fill: dists >= 0 -> identity for max
}

// ---------------- FPS: one block/batch, 4 waves x 8 pts/lane, exact fp32 ----------
// pk-pair distance update (R7-verified numerics). Wave argmax: value-only DPP max ->
// readlane(63) -> ballot(==) -> ffs -> readlane(bestloc). Cross-wave: u64 key slots,
// one barrier; 12 speculative broadcast coord reads overlap the 3-key-max tree.
// Reference scan emits PRE-update far (idx[0]==0) -> record at loop top.
__global__ __launch_bounds__(256) void fps_kernel(const float* __restrict__ coords,
                                                  int* __restrict__ fidx,
                                                  float* __restrict__ out_xyz) {
  int b = blockIdx.x;
  const float* cb = coords + (size_t)b * (N_ * 3);
  __shared__ float sptx[N_], spty[N_], sptz[N_];
  __shared__ ull   skey[2][4];
  __shared__ int   sfar[S_];
  int tid = threadIdx.x, lane = tid & 63, wid = tid >> 6;
  for (int j = tid; j < N_; j += 256) {
    sptx[j] = cb[3 * j]; spty[j] = cb[3 * j + 1]; sptz[j] = cb[3 * j + 2];
  }
  f32x2 px[4], py[4], pz[4], dist[4];
  int j0 = tid * 8;
#pragma unroll
  for (int p = 0; p < 4; ++p) {
    int j = j0 + 2 * p;
    px[p].x = cb[3 * j];     py[p].x = cb[3 * j + 1]; pz[p].x = cb[3 * j + 2];
    px[p].y = cb[3 * j + 3]; py[p].y = cb[3 * j + 4]; pz[p].y = cb[3 * j + 5];
    dist[p].x = 1e10f; dist[p].y = 1e10f;
  }
  float cx = cb[0], cy = cb[1], cz = cb[2];
  uint far = 0;
  __syncthreads();
  for (int s = 0; s < S_; ++s) {
    if (tid == 0) sfar[s] = (int)far;          // PRE-update far (matches jax scan)
    f32x2 c2x = {cx, cx}, c2y = {cy, cy}, c2z = {cz, cz};
    float bestv = -1.f; uint bestloc = 0;
#pragma unroll
    for (int p = 0; p < 4; ++p) {
      f32x2 dx, dy, dz, qx, qy, qz, s1, s2;
      asm("v_pk_add_f32 %0, %1, %2 neg_lo:[0,1] neg_hi:[0,1]" : "=v"(dx) : "v"(px[p]), "v"(c2x));
      asm("v_pk_add_f32 %0, %1, %2 neg_lo:[0,1] neg_hi:[0,1]" : "=v"(dy) : "v"(py[p]), "v"(c2y));
      asm("v_pk_add_f32 %0, %1, %2 neg_lo:[0,1] neg_hi:[0,1]" : "=v"(dz) : "v"(pz[p]), "v"(c2z));
      asm("v_pk_mul_f32 %0, %1, %1" : "=v"(qx) : "v"(dx));
      asm("v_pk_mul_f32 %0, %1, %1" : "=v"(qy) : "v"(dy));
      asm("v_pk_mul_f32 %0, %1, %1" : "=v"(qz) : "v"(dz));
      asm("v_pk_add_f32 %0, %1, %2" : "=v"(s1) : "v"(qx), "v"(qy));
      asm("v_pk_add_f32 %0, %1, %2" : "=v"(s2) : "v"(s1), "v"(qz));
      float n0 = fminf(dist[p].x, s2.x);
      float n1 = fminf(dist[p].y, s2.y);
      dist[p].x = n0; dist[p].y = n1;
      bool g0 = n0 > bestv; bestv = g0 ? n0 : bestv; bestloc = g0 ? (uint)(2 * p) : bestloc;
      bool g1 = n1 > bestv; bestv = g1 ? n1 : bestv; bestloc = g1 ? (uint)(2 * p + 1) : bestloc;
    }
    // wave64 value-max (6 dpp+max, lands full in lane 63)
    float m = bestv;
    m = dpp_fmax_step<0x111, 0xf>(m);   // row_shr:1
    m = dpp_fmax_step<0x112, 0xf>(m);   // row_shr:2
    m = dpp_fmax_step<0x114, 0xf>(m);   // row_shr:4
    m = dpp_fmax_step<0x118, 0xf>(m);   // row_shr:8
    m = dpp_fmax_step<0x142, 0xa>(m);   // row_bcast:15 -> rows 1,3
    m = dpp_fmax_step<0x143, 0xc>(m);   // row_bcast:31 -> rows 2,3
    float wmax = __uint_as_float((uint)__builtin_amdgcn_readlane((int)__float_as_uint(m), 63));
    ull mask = __ballot(bestv == wmax);
    int wl = __ffsll((long long)mask) - 1;            // first lane = smallest j
    uint loc = (uint)__builtin_amdgcn_readlane((int)bestloc, wl);
    uint jg = (uint)(((wid << 6) + wl) * 8) + loc;    // wave-winner global index
    int pb = s & 1;
    if (lane == 0) skey[pb][wid] = ((ull)__float_as_uint(wmax) << 32) | (ull)(~jg);
    __syncthreads();                                  // lgkm-only barrier
    ull k0 = skey[pb][0], k1 = skey[pb][1], k2 = skey[pb][2], k3 = skey[pb][3];
    uint w0 = ~(uint)k0, w1 = ~(uint)k1, w2 = ~(uint)k2, w3 = ~(uint)k3;
    float x0 = sptx[w0], y0 = spty[w0], z0 = sptz[w0];   // 12 speculative broadcast
    float x1 = sptx[w1], y1 = spty[w1], z1 = sptz[w1];   // reads, overlap the tree
    float x2 = sptx[w2], y2 = spty[w2], z2 = sptz[w2];
    float x3 = sptx[w3], y3 = spty[w3], z3 = sptz[w3];
    bool t01 = k0 > k1, t23 = k2 > k3;
    ull ka = t01 ? k0 : k1;  float xa = t01 ? x0 : x1, ya = t01 ? y0 : y1, za = t01 ? z0 : z1;
    ull kb = t23 ? k2 : k3;  float xb = t23 ? x2 : x3, yb = t23 ? y2 : y3, zb = t23 ? z2 : z3;
    bool tw = ka > kb;
    far = ~(uint)(tw ? ka : kb);
    cx = tw ? xa : xb; cy = tw ? ya : yb; cz = tw ? za : zb;
  }
  __syncthreads();
  for (int s2 = tid; s2 < S_; s2 += 256) {
    int f = sfar[s2];
    fidx[b * S_ + s2] = f;
    int o = (b * S_ + s2) * 3;
    out_xyz[o] = sptx[f]; out_xyz[o + 1] = spty[f]; out_xyz[o + 2] = sptz[f];
  }
}

// ---------------- Ball query: one wave per centroid ----------------
__global__ __launch_bounds__(256) void ball_kernel(const float* __restrict__ coords,
                                                   const int* __restrict__ fidx,
                                                   int* __restrict__ gidx) {
  int lane = threadIdx.x & 63;
  int g = __builtin_amdgcn_readfirstlane(blockIdx.x * 4 + (threadIdx.x >> 6));
  int b = g >> 9;
  const float* cb = coords + (size_t)b * (N_ * 3);
  int nf = fidx[g];
  float cx = cb[3 * nf], cy = cb[3 * nf + 1], cz = cb[3 * nf + 2];
  int* out = gidx + g * K_;
  int cnt = 0, first = 0;
  bool hasfirst = false;
  for (int base = 0; base < N_; base += 64) {
    int j = base + lane;
    float dx = __fsub_rn(cb[3 * j], cx);
    float dy = __fsub_rn(cb[3 * j + 1], cy);
    float dz = __fsub_rn(cb[3 * j + 2], cz);
    float d = __fadd_rn(__fadd_rn(__fmul_rn(dx, dx), __fmul_rn(dy, dy)), __fmul_rn(dz, dz));
    bool in = (d <= 0.25f);     // kept iff sqr <= r^2 (ref excludes sqr > r^2)
    ull m = __ballot(in);
    if (in) {
      int pos = cnt + __popcll(m & ((1ull << lane) - 1ull));
      if (pos < K_) out[pos] = j;
    }
    if (!hasfirst && m) { first = base + (__ffsll((long long)m) - 1); hasfirst = true; }
    cnt += __popcll(m);
    if (cnt >= K_) break;
  }
  if (cnt < K_) {
    for (int p = cnt + lane; p < K_; p += 64) out[p] = first;
  }
}

// ---------------- prep: B-fragment packs for both GEMMs ----------------
__global__ __launch_bounds__(256) void prep_kernel(const float* __restrict__ W1,
                                                   const float* __restrict__ W2,
                                                   ushort_t* __restrict__ Bp1,
                                                   ushort_t* __restrict__ Bpd,
                                                   ushort_t* __restrict__ Bp2) {
  int i = blockIdx.x * 256 + threadIdx.x;   // 16384
  int j2 = i & 7, l = (i >> 3) & 63;
  {
    int kc = (i >> 9) & 3, nt = i >> 11;
    int o2 = nt * 16 + (l & 15);
    int c2 = kc * 32 + ((l >> 4) * 8) + j2;
    Bp2[i] = (ushort_t)bf16b(W2[o2 * 128 + c2]);
  }
  if (i < 8192) {
    int kc = (i >> 9) & 1, nt = (i >> 10) & 7;
    int o2 = nt * 16 + (l & 15);
    int c2 = kc * 32 + ((l >> 4) * 8) + j2;
    float wa = W1[o2 * 128 + c2];
    float wb = W1[o2 * 128 + 64 + c2];
    Bp1[i] = (ushort_t)bf16b(wa);
    Bpd[i] = (ushort_t)bf16b(wb - wa);
  }
}

// ---------------- GEMM1 (MFMA bf16): h1T[g][k][o] = W1a@xg + (W1b-W1a)@ctr ------
__global__ __launch_bounds__(256) void gemm1_kernel(const float* __restrict__ x,
    const int* __restrict__ fidx, const int* __restrict__ gidx,
    const ushort_t* __restrict__ Bp1, const ushort_t* __restrict__ Bpd,
    ushort_t* __restrict__ h1T, float* __restrict__ psum, float* __restrict__ psq) {
  __shared__ ushort_t xgT[4][32 * ATS1];
  __shared__ float sctr[4][DIN];
  int tid = threadIdx.x;
  int lane = tid & 63, wid = tid >> 6;
  int g = __builtin_amdgcn_readfirstlane(blockIdx.x * 4 + wid);
  int b = g >> 9;
  const float* xb = x + (size_t)b * (DIN * N_);
  int nf = fidx[g];
  sctr[wid][lane] = xb[(size_t)lane * N_ + nf];   // lane = c (0..63)
  int kk = lane & 31, ch = lane >> 5;
  int gik = gidx[g * K_ + kk];
  ushort_t* xw = xgT[wid];
#pragma unroll
  for (int cc = 0; cc < 32; ++cc) {
    int c = ch * 32 + cc;
    xw[kk * ATS1 + c] = (ushort_t)bf16b(xb[(size_t)c * N_ + gik]);
  }
  __syncthreads();
  int l15 = lane & 15, r8 = (lane >> 4) * 8;
  f32x4 acc[2][8];
#pragma unroll
  for (int nt = 0; nt < 8; ++nt) acc[0][nt] = (f32x4){0.f, 0.f, 0.f, 0.f};
#pragma unroll
  for (int kc = 0; kc < 2; ++kc) {
    union { bf16x8 v; ushort_t u[8]; } cu;
#pragma unroll
    for (int j = 0; j < 8; ++j) cu.u[j] = (ushort_t)bf16b(sctr[wid][kc * 32 + r8 + j]);
#pragma unroll
    for (int nt = 0; nt < 8; ++nt) {
      bf16x8 bf = *(const bf16x8*)(Bpd + ((nt * 2 + kc) * 64 + lane) * 8);
      acc[0][nt] = __builtin_amdgcn_mfma_f32_16x16x32_bf16(cu.v, bf, acc[0][nt], 0, 0, 0);
    }
  }
#pragma unroll
  for (int nt = 0; nt < 8; ++nt) acc[1][nt] = acc[0][nt];
#pragma unroll
  for (int kc = 0; kc < 2; ++kc) {
    bf16x8 afrag[2];
#pragma unroll
    for (int mt = 0; mt < 2; ++mt)
      afrag[mt] = *(const bf16x8*)(xw + (mt * 16 + l15) * ATS1 + kc * 32 + r8);
#pragma unroll
    for (int nt = 0; nt < 8; ++nt) {
      bf16x8 bf = *(const bf16x8*)(Bp1 + ((nt * 2 + kc) * 64 + lane) * 8);
      acc[0][nt] = __builtin_amdgcn_mfma_f32_16x16x32_bf16(afrag[0], bf, acc[0][nt], 0, 0, 0);
      acc[1][nt] = __builtin_amdgcn_mfma_f32_16x16x32_bf16(afrag[1], bf, acc[1][nt], 0, 0, 0);
    }
  }
#pragma unroll
  for (int nt = 0; nt < 8; ++nt) {
    float s = 0.f, q = 0.f;
#pragma unroll
    for (int mt = 0; mt < 2; ++mt)
#pragma unroll
      for (int r = 0; r < 4; ++r) { float a = acc[mt][nt][r]; s += a; q = fmaf(a, a, q); }
    s += __shfl_xor(s, 16, 64); s += __shfl_xor(s, 32, 64);
    q += __shfl_xor(q, 16, 64); q += __shfl_xor(q, 32, 64);
    if (lane < 16) {
      int o = nt * 16 + lane;
      psum[o * G_ + g] = s; psq[o * G_ + g] = q;
    }
  }
#pragma unroll
  for (int mt = 0; mt < 2; ++mt)
#pragma unroll
    for (int r = 0; r < 4; ++r) {
      int k = mt * 16 + (lane >> 4) * 4 + r;
      ushort_t* dst = h1T + (size_t)g * 4096 + k * 128 + l15;
#pragma unroll
      for (int nt = 0; nt < 8; ++nt)
        dst[nt * 16] = (ushort_t)bf16b(acc[mt][nt][r]);
    }
}

// ---------------- BN finalize: per-channel mean/var -> scale/shift ----------------
__global__ __launch_bounds__(256) void bn_finalize(const float* __restrict__ psum,
    const float* __restrict__ psq, const float* __restrict__ gamma,
    const float* __restrict__ beta, float* __restrict__ bnp) {
  int o = blockIdx.x, tid = threadIdx.x;
  double s = 0.0, q = 0.0;
  for (int g = tid; g < G_; g += 256) { s += (double)psum[o * G_ + g]; q += (double)psq[o * G_ + g]; }
  __shared__ double ss[256], qq[256];
  ss[tid] = s; qq[tid] = q; __syncthreads();
  for (int off = 128; off > 0; off >>= 1) {
    if (tid < off) { ss[tid] += ss[tid + off]; qq[tid] += qq[tid + off]; }
    __syncthreads();
  }
  if (tid == 0) {
    double n = 262144.0;
    double mean = ss[0] / n, var = qq[0] / n - mean * mean;
    float scv = (float)((double)gamma[o] / sqrt(var + 1e-5));
    bnp[2 * o] = scv;
    bnp[2 * o + 1] = (float)((double)beta[o] - mean * (double)scv);
  }
}

// ---------------- GEMM2 (MFMA bf16): CT layout D[k][o], per-(g,o) stats ----------
__global__ __launch_bounds__(256) void gemm2_kernel(const ushort_t* __restrict__ h1T,
    const ushort_t* __restrict__ Bp2, const float* __restrict__ bnp1,
    float* __restrict__ psum, float* __restrict__ psq,
    float* __restrict__ hmax, float* __restrict__ hmin) {
  __shared__ ushort_t actT[4][32 * ATS];
  int tid = threadIdx.x;
  int lane = tid & 63, wid = tid >> 6;
  int g = __builtin_amdgcn_readfirstlane(blockIdx.x * 4 + wid);
  ushort_t* aw = actT[wid];
  int c0 = (lane & 15) * 8;
  float s1[8], t1[8];
#pragma unroll
  for (int jj = 0; jj < 8; ++jj) { s1[jj] = bnp1[2 * (c0 + jj)]; t1[jj] = bnp1[2 * (c0 + jj) + 1]; }
  const uint4* src = (const uint4*)(h1T + (size_t)g * 4096);
#pragma unroll
  for (int t = 0; t < 8; ++t) {
    int idx = t * 64 + lane;
    uint4 v = src[idx];
    int k = idx >> 4;
    uint w[4] = {v.x, v.y, v.z, v.w};
    uint o4[4];
#pragma unroll
    for (int p2 = 0; p2 < 4; ++p2) {
      float a0 = fmaxf(fmaf(bf2f(w[p2] & 0xffffu), s1[2 * p2], t1[2 * p2]), 0.f);
      float a1 = fmaxf(fmaf(bf2f(w[p2] >> 16), s1[2 * p2 + 1], t1[2 * p2 + 1]), 0.f);
      o4[p2] = (bf16b(a1) << 16) | bf16b(a0);
    }
    *(uint4*)(aw + k * ATS + c0) = make_uint4(o4[0], o4[1], o4[2], o4[3]);
  }
  __syncthreads();
  f32x4 acc[2][8];
#pragma unroll
  for (int mt = 0; mt < 2; ++mt)
#pragma unroll
    for (int nt = 0; nt < 8; ++nt) acc[mt][nt] = (f32x4){0.f, 0.f, 0.f, 0.f};
#pragma unroll
  for (int kc = 0; kc < 4; ++kc) {
    bf16x8 afrag[2];
#pragma unroll
    for (int mt = 0; mt < 2; ++mt)
      afrag[mt] = *(const bf16x8*)(aw + (mt * 16 + (lane & 15)) * ATS + kc * 32 + (lane >> 4) * 8);
#pragma unroll
    for (int nt = 0; nt < 8; ++nt) {
      bf16x8 bfrag = *(const bf16x8*)(Bp2 + ((nt * 4 + kc) * 64 + lane) * 8);
      acc[0][nt] = __builtin_amdgcn_mfma_f32_16x16x32_bf16(afrag[0], bfrag, acc[0][nt], 0, 0, 0);
      acc[1][nt] = __builtin_amdgcn_mfma_f32_16x16x32_bf16(afrag[1], bfrag, acc[1][nt], 0, 0, 0);
    }
  }
#pragma unroll
  for (int nt = 0; nt < 8; ++nt) {
    float s = 0.f, q = 0.f, mx = -1e30f, mn = 1e30f;
#pragma unroll
    for (int mt = 0; mt < 2; ++mt)
#pragma unroll
      for (int r = 0; r < 4; ++r) {
        float a = acc[mt][nt][r];
        s += a; q = fmaf(a, a, q); mx = fmaxf(mx, a); mn = fminf(mn, a);
      }
    s += __shfl_xor(s, 16, 64); s += __shfl_xor(s, 32, 64);
    q += __shfl_xor(q, 16, 64); q += __shfl_xor(q, 32, 64);
    mx = fmaxf(mx, __shfl_xor(mx, 16, 64)); mx = fmaxf(mx, __shfl_xor(mx, 32, 64));
    mn = fminf(mn, __shfl_xor(mn, 16, 64)); mn = fminf(mn, __shfl_xor(mn, 32, 64));
    if (lane < 16) {
      int o = nt * 16 + lane;
      psum[o * G_ + g] = s; psq[o * G_ + g] = q;
      hmax[o * G_ + g] = mx; hmin[o * G_ + g] = mn;
    }
  }
}

// ---------------- pool: out[b,o,s] = relu(s2 * (s2>=0 ? max : min) + t2) ----------------
__global__ __launch_bounds__(256) void pool_kernel(const float* __restrict__ hmax,
    const float* __restrict__ hmin, const float* __restrict__ bnp2,
    float* __restrict__ out) {
  int i = blockIdx.x * 256 + threadIdx.x;   // 1,048,576 = (b*128+o)*512+s
  int s = i & 511;
  int o = (i >> 9) & 127;
  int b = i >> 16;
  int g = b * 512 + s;
  float scv = bnp2[2 * o], tf = bnp2[2 * o + 1];
  float v = (scv >= 0.f) ? hmax[o * G_ + g] : hmin[o * G_ + g];
  out[i] = fmaxf(fmaf(scv, v, tf), 0.f);
}

extern "C" void kernel_launch(void* const* d_in, const int* in_sizes, int n_in,
                              void* d_out, int out_size, void* d_ws, size_t ws_size,
                              hipStream_t stream) {
  const float* x      = (const float*)d_in[0];
  const float* coords = (const float*)d_in[1];
  const float* W1     = (const float*)d_in[2];
  const float* W2     = (const float*)d_in[3];
  const float* gamma1 = (const float*)d_in[4];
  const float* beta1  = (const float*)d_in[5];
  const float* gamma2 = (const float*)d_in[6];
  const float* beta2  = (const float*)d_in[7];
  float* out = (float*)d_out;
  char* ws = (char*)d_ws;
  ushort_t* h1T  = (ushort_t*)(ws);               // 67,108,864 B  (h1T[g][k][o] bf16)
  float* psum1 = (float*)(ws + 67108864);         // 4 MB each below
  float* psq1  = (float*)(ws + 71303168);
  float* psum2 = (float*)(ws + 75497472);
  float* psq2  = (float*)(ws + 79691776);
  float* hmax  = (float*)(ws + 83886080);
  float* hmin  = (float*)(ws + 88080384);
  ushort_t* Bp1 = (ushort_t*)(ws + 92274688);     // 16 KB
  ushort_t* Bpd = (ushort_t*)(ws + 92291072);     // 16 KB
  ushort_t* Bp2 = (ushort_t*)(ws + 92307456);     // 32 KB
  float* bnp1  = (float*)(ws + 92340224);
  float* bnp2  = (float*)(ws + 92341248);
  int* fidx    = (int*)(ws + 92342272);           // 32 KB
  int* gidx    = (int*)(ws + 92375040);           // 1 MB, end 93,423,616 B

  prep_kernel<<<64, 256, 0, stream>>>(W1, W2, Bp1, Bpd, Bp2);
  fps_kernel<<<16, 256, 0, stream>>>(coords, fidx, out);
  ball_kernel<<<2048, 256, 0, stream>>>(coords, fidx, gidx);
  gemm1_kernel<<<2048, 256, 0, stream>>>(x, fidx, gidx, Bp1, Bpd, h1T, psum1, psq1);
  bn_finalize<<<128, 256, 0, stream>>>(psum1, psq1, gamma1, beta1, bnp1);
  gemm2_kernel<<<2048, 256, 0, stream>>>(h1T, Bp2, bnp1, psum2, psq2, hmax, hmin);
  bn_finalize<<<128, 256, 0, stream>>>(psum2, psq2, gamma2, beta2, bnp2);
  pool_kernel<<<4096, 256, 0, stream>>>(hmax, hmin, bnp2, out + 24576);
}